// Round 3
// baseline (40980.713 us; speedup 1.0000x reference)
//
#include <hip/hip_runtime.h>
#include <stdint.h>

// AutoRegressiveModel: 47 outer x 512 inner sequential LSTM steps (mid=256).
// Bernoulli sampling bit-matches JAX threefry2x32 (partitionable mode).
//
// R3 structure: 161 blocks x 256 threads.
//   blocks 0..63  : LSTM workers — ONE wave each (tid<64; rest exit).
//                   Wave owns h[4b..4b+4); lane l: gate g=l>>4, row jj=(l>>2)&3,
//                   col-quarter q=l&3; 64 fp32 W_hh weights in VGPRs.
//                   Barrier-free step loop: poll all 256 tagged h words
//                   (4/lane, 2-deep pipelined), stage via private LDS copy
//                   (1 wave/CU -> no LDS pipe contention), shfl reductions.
//   block 64      : init + sampler (threefry RNG, logprob/entropy, obs feed).
//   blocks 65..160: DVFS heaters — register FMA spin until done flag.

#define MID      256
#define NOUT     48
#define NSEQ     512
#define NOUTER   47
#define NSTEP    (NOUTER * NSEQ)   // 24064
#define NWRK     64
#define SAMP_BLK 64
#define NHEAT    96
#define MAGIC_V  0x1234ABCDu
#define DONE_V   0x0D0E0D0Eu
#define LOG2E    1.4426950408889634f

#define AL_RELAX(p)    __hip_atomic_load((p), __ATOMIC_RELAXED, __HIP_MEMORY_SCOPE_AGENT)
#define AL_ACQ(p)      __hip_atomic_load((p), __ATOMIC_ACQUIRE, __HIP_MEMORY_SCOPE_AGENT)
#define AS_RELAX(p, v) __hip_atomic_store((p), (v), __ATOMIC_RELAXED, __HIP_MEMORY_SCOPE_AGENT)
#define AS_REL(p, v)   __hip_atomic_store((p), (v), __ATOMIC_RELEASE, __HIP_MEMORY_SCOPE_AGENT)

__device__ __forceinline__ uint32_t rotl32(uint32_t x, int d) {
  return (x << d) | (x >> (32 - d));
}

// Exact JAX threefry2x32 (20 rounds).
__device__ __forceinline__ void threefry2x32(uint32_t k0, uint32_t k1,
                                             uint32_t x0, uint32_t x1,
                                             uint32_t& o0, uint32_t& o1) {
  uint32_t ks2 = k0 ^ k1 ^ 0x1BD11BDAu;
  uint32_t v0 = x0 + k0, v1 = x1 + k1;
#define TF_R(r) { v0 += v1; v1 = rotl32(v1, r); v1 ^= v0; }
  TF_R(13) TF_R(15) TF_R(26) TF_R(6)
  v0 += k1;  v1 += ks2 + 1u;
  TF_R(17) TF_R(29) TF_R(16) TF_R(24)
  v0 += ks2; v1 += k0 + 2u;
  TF_R(13) TF_R(15) TF_R(26) TF_R(6)
  v0 += k0;  v1 += k1 + 3u;
  TF_R(17) TF_R(29) TF_R(16) TF_R(24)
  v0 += k1;  v1 += ks2 + 4u;
  TF_R(13) TF_R(15) TF_R(26) TF_R(6)
  v0 += ks2; v1 += k0 + 5u;
#undef TF_R
  o0 = v0; o1 = v1;
}

__device__ __forceinline__ float sigf(float x) { return 1.0f / (1.0f + expf(-x)); }

__device__ __forceinline__ uint64_t packht(float h, uint32_t tag) {
  return ((uint64_t)tag << 32) | (uint64_t)__float_as_uint(h);
}

__global__ __launch_bounds__(256, 1)
void arlstm_kernel(const float* __restrict__ W_ih, const float* __restrict__ W_hh,
                   const float* __restrict__ b_ih, const float* __restrict__ b_hh,
                   const float* __restrict__ W_out, const float* __restrict__ b_out,
                   float* __restrict__ out, uint64_t* __restrict__ ws) {
  // ws layout (u64 units):
  uint64_t* h_hist = ws;                                  // [512][256] tagged
  float*    obsbuf = (float*)(ws + 512 * 256);            // [2][512][2]
  uint32_t* p_prog = (uint32_t*)(obsbuf + 2 * 512 * 2);   // [4] sampler progress
  uint32_t* magic  = p_prog + 16;
  uint32_t* done   = p_prog + 17;
  float*    heat   = (float*)(p_prog + 32);               // heater sink

  const int tid = threadIdx.x;
  const int blk = blockIdx.x;

  __shared__ __align__(16) float4 hstage4[64];  // worker: private h copy
  __shared__ float lp_acc[512];
  __shared__ float ent_acc[512];
  __shared__ float red[256];

  if (blk >= NWRK + 1) {
    // ------------------------- DVFS heater -------------------------
    float h0 = (float)tid * 1.1f + 0.1f, h1 = h0 + 0.7f, h2 = h0 + 1.3f, h3 = h0 + 2.9f;
    const float ca = 1.0000001f, cb = 1e-7f;
    while (AL_RELAX(done) != DONE_V) {
#pragma unroll 64
      for (int i = 0; i < 1024; ++i) {
        h0 = __builtin_fmaf(h0, ca, cb);
        h1 = __builtin_fmaf(h1, ca, cb);
        h2 = __builtin_fmaf(h2, ca, cb);
        h3 = __builtin_fmaf(h3, ca, cb);
      }
    }
    if (tid == 0) heat[blk - NWRK - 1 + 0] = (h0 + h1) + (h2 + h3);
    return;
  }

  if (blk == SAMP_BLK) {
    // ----------------------- init + sampler block -----------------------
    AS_RELAX(&h_hist[tid], 0ull);     // h_0 = 0 with tag 0
    if (tid < 16) AS_RELAX(&p_prog[tid], 0u);
    out[(tid)       * NOUT] = 0.0f;   // samples column 0 = zeros
    out[(tid + 256) * NOUT] = 0.0f;
    lp_acc[tid] = 0.0f;  lp_acc[tid + 256] = 0.0f;
    ent_acc[tid] = 0.0f; ent_acc[tid + 256] = 0.0f;
    __threadfence();
    __syncthreads();
    if (tid == 0) AS_REL(magic, MAGIC_V);

    const int w    = tid >> 6;   // wave 0..3 handles steps s with (s-1)&3 == w
    const int lane = tid & 63;
    const float wo0 = W_out[lane * 4 + 0], wo1 = W_out[lane * 4 + 1];
    const float wo2 = W_out[lane * 4 + 2], wo3 = W_out[lane * 4 + 3];
    const float bo = b_out[0];

    for (int s = w + 1; s <= NSTEP; s += 4) {
      const int k = (s - 1) >> 9;
      const int t = (s - 1) & 511;
      uint64_t* src = h_hist + (uint64_t)(s & 511) * 256 + lane * 4;
      uint64_t v0, v1, v2, v3;
      for (;;) {
        v0 = AL_RELAX(src + 0);
        v1 = AL_RELAX(src + 1);
        v2 = AL_RELAX(src + 2);
        v3 = AL_RELAX(src + 3);
        int ok = ((uint32_t)(v0 >> 32) == (uint32_t)s) &
                 ((uint32_t)(v1 >> 32) == (uint32_t)s) &
                 ((uint32_t)(v2 >> 32) == (uint32_t)s) &
                 ((uint32_t)(v3 >> 32) == (uint32_t)s);
        if (__all(ok)) break;
      }
      float zp = fmaf(__uint_as_float((uint32_t)v0), wo0,
                 fmaf(__uint_as_float((uint32_t)v1), wo1,
                 fmaf(__uint_as_float((uint32_t)v2), wo2,
                      __uint_as_float((uint32_t)v3) * wo3)));
      zp += __shfl_xor(zp, 1);
      zp += __shfl_xor(zp, 2);
      zp += __shfl_xor(zp, 4);
      zp += __shfl_xor(zp, 8);
      zp += __shfl_xor(zp, 16);
      zp += __shfl_xor(zp, 32);
      const float p = sigf(zp + bo);

      // JAX partitionable threefry: key_k = tf((0,42),(0,k)); bits = xor of
      // tf(key_k,(0,t)); u = bitcast((bits>>9)|0x3f800000)-1; sample = u < p.
      uint32_t ka, kb, c1, c2;
      threefry2x32(0u, 42u, 0u, (uint32_t)k, ka, kb);
      threefry2x32(ka, kb, 0u, (uint32_t)t, c1, c2);
      const uint32_t bits = c1 ^ c2;
      const float u = __uint_as_float((bits >> 9) | 0x3f800000u) - 1.0f;
      const float smp = (u < p) ? 1.0f : 0.0f;

      if (lane == 0) {
        uint32_t* ob = (uint32_t*)(obsbuf + ((k + 1) & 1) * (512 * 2) + t * 2);
        AS_RELAX(&ob[0], __float_as_uint(smp));
        AS_RELAX(&ob[1], __float_as_uint(p));
        AS_REL(&p_prog[w], (uint32_t)s);
        out[t * NOUT + (k + 1)] = smp;
        const float lg = logf(p), lg1 = log1pf(-p);
        lp_acc[t]  += (smp > 0.5f) ? lg : lg1;
        ent_acc[t] -= (p * lg + (1.0f - p) * lg1);
      }
    }
    __syncthreads();
    // final outputs: logprobs (centered), entropies (mean over 47)
    red[tid] = lp_acc[tid] + lp_acc[tid + 256];
    __syncthreads();
    for (int off = 128; off > 0; off >>= 1) {
      if (tid < off) red[tid] += red[tid + off];
      __syncthreads();
    }
    const float mean = red[0] * (1.0f / 512.0f);
    out[24576 + tid]        = lp_acc[tid]        - mean;
    out[24576 + 256 + tid]  = lp_acc[tid + 256]  - mean;
    out[25088 + tid]        = ent_acc[tid]       * (1.0f / 47.0f);
    out[25088 + 256 + tid]  = ent_acc[tid + 256] * (1.0f / 47.0f);
    __syncthreads();
    if (tid == 0) { __threadfence(); AS_REL(done, DONE_V); }
    return;
  }

  // ----------------------------- LSTM worker -----------------------------
  if (tid >= 64) return;                 // one wave per block
  const int l  = tid;
  const int g  = l >> 4;                 // gate 0..3 (i,f,g,o)
  const int jj = (l >> 2) & 3;           // h element within block
  const int q  = l & 3;                  // column quarter
  const int u  = l >> 2;                 // poll-run index 0..15
  const int row = g * 256 + blk * 4 + jj;

  float4 wf[16];
#pragma unroll
  for (int i = 0; i < 16; ++i)
    wf[i] = ((const float4*)(W_hh + (uint64_t)row * 256 + q * 64))[i];

  const float bb  = b_ih[row] + b_hh[row];
  const float wx0 = W_ih[row * 2 + 0];
  const float wx1 = W_ih[row * 2 + 1];
  const float mconst = (g == 2) ? (-2.0f * LOG2E) : (-LOG2E);
  const float ml     = (g == 2) ? 2.0f : 1.0f;
  const float ad     = (g == 2) ? -1.0f : 0.0f;

  while (AL_ACQ(magic) != MAGIC_V) {}   // all lanes spin on same addr

  float c_st = 0.0f;                    // redundant x4 on lanes l<16
  const int hidx = blk * 4 + jj;        // produced h element (q==0,g==0 lanes)
  const int poff = q * 64 + u * 4;      // this lane's 4-word poll run

  for (int s = 1; s <= NSTEP; ++s) {
    const int k = (s - 1) >> 9;
    const int t = (s - 1) & 511;

    float sxf = 0.0f, pxf = 0.0f;       // lane 63 carries obs
    if (l == 63 && k > 0) {
      const uint32_t X = (uint32_t)((k - 1) * 512 + t + 1);
      while (AL_ACQ(&p_prog[t & 3]) < X) {}
      uint32_t* ob = (uint32_t*)(obsbuf + (k & 1) * (512 * 2) + t * 2);
      sxf = __uint_as_float(AL_RELAX(&ob[0]));
      pxf = __uint_as_float(AL_RELAX(&ob[1]));
    }

    // ---- poll own 4 tagged words of h_{s-1} (2-deep pipelined) ----
    uint64_t* src = h_hist + (uint64_t)((s - 1) & 511) * 256 + poff;
    const uint32_t want = (uint32_t)(s - 1);
    uint64_t a0 = AL_RELAX(src + 0), a1 = AL_RELAX(src + 1);
    uint64_t a2 = AL_RELAX(src + 2), a3 = AL_RELAX(src + 3);
#define TAGS_OK(x0,x1,x2,x3) \
    (((uint32_t)((x0) >> 32) == want) & ((uint32_t)((x1) >> 32) == want) & \
     ((uint32_t)((x2) >> 32) == want) & ((uint32_t)((x3) >> 32) == want))
    if (!__all(TAGS_OK(a0, a1, a2, a3))) {
      uint64_t b0 = AL_RELAX(src + 0), b1 = AL_RELAX(src + 1);
      uint64_t b2 = AL_RELAX(src + 2), b3 = AL_RELAX(src + 3);
      for (;;) {
        if (__all(TAGS_OK(a0, a1, a2, a3))) break;
        a0 = AL_RELAX(src + 0); a1 = AL_RELAX(src + 1);
        a2 = AL_RELAX(src + 2); a3 = AL_RELAX(src + 3);
        if (__all(TAGS_OK(b0, b1, b2, b3))) {
          a0 = b0; a1 = b1; a2 = b2; a3 = b3; break;
        }
        b0 = AL_RELAX(src + 0); b1 = AL_RELAX(src + 1);
        b2 = AL_RELAX(src + 2); b3 = AL_RELAX(src + 3);
      }
    }
#undef TAGS_OK

    // ---- stage into private LDS copy (wave-lockstep; explicit lgkm wait) ----
    hstage4[u + q * 16] = make_float4(
        __uint_as_float((uint32_t)a0), __uint_as_float((uint32_t)a1),
        __uint_as_float((uint32_t)a2), __uint_as_float((uint32_t)a3));
    __asm__ volatile("s_waitcnt lgkmcnt(0)" ::: "memory");

    // ---- matvec: 64 cols of quarter q against this lane's row ----
    const float4* hs = &hstage4[q * 16];
    float p0 = 0.f, p1 = 0.f, p2 = 0.f, p3 = 0.f;
#pragma unroll
    for (int i = 0; i < 16; ++i) {
      const float4 hv = hs[i];
      p0 = fmaf(wf[i].x, hv.x, p0);
      p1 = fmaf(wf[i].y, hv.y, p1);
      p2 = fmaf(wf[i].z, hv.z, p2);
      p3 = fmaf(wf[i].w, hv.w, p3);
    }
    float dot = (p0 + p1) + (p2 + p3);
    dot += __shfl_xor(dot, 1);
    dot += __shfl_xor(dot, 2);          // full row dot on all 4 q-lanes

    const float sx = __shfl(sxf, 63);
    const float px = __shfl(pxf, 63);
    const float gv = dot + fmaf(wx0, sx, fmaf(wx1, px, bb));
    const float e   = __builtin_amdgcn_exp2f(gv * mconst);
    const float y   = __builtin_amdgcn_rcpf(1.0f + e);
    const float act = __builtin_fmaf(ml, y, ad);

    const float a_f = __shfl(act, (l + 16) & 63);
    const float a_g = __shfl(act, (l + 32) & 63);
    const float a_o = __shfl(act, (l + 48) & 63);

    if (l < 16) {                       // g==0 lanes: act = sig(i)
      c_st = a_f * c_st + act * a_g;
      const float ec = __builtin_amdgcn_exp2f(c_st * (-2.0f * LOG2E));
      const float yc = __builtin_amdgcn_rcpf(1.0f + ec);
      const float th = __builtin_fmaf(2.0f, yc, -1.0f);
      const float hnew = a_o * th;
      if (q == 0)
        AS_RELAX(&h_hist[(uint64_t)(s & 511) * 256 + hidx], packht(hnew, (uint32_t)s));
    }
  }
}

extern "C" void kernel_launch(void* const* d_in, const int* in_sizes, int n_in,
                              void* d_out, int out_size, void* d_ws, size_t ws_size,
                              hipStream_t stream) {
  const float* W_ih  = (const float*)d_in[0];
  const float* W_hh  = (const float*)d_in[1];
  const float* b_ih  = (const float*)d_in[2];
  const float* b_hh  = (const float*)d_in[3];
  const float* W_out = (const float*)d_in[4];
  const float* b_out = (const float*)d_in[5];
  float* out = (float*)d_out;
  uint64_t* ws = (uint64_t*)d_ws;

  arlstm_kernel<<<dim3(NWRK + 1 + NHEAT), dim3(256), 0, stream>>>(
      W_ih, W_hh, b_ih, b_hh, W_out, b_out, out, ws);
}

// Round 4
// 40744.672 us; speedup vs baseline: 1.0058x; 1.0058x over previous
//
#include <hip/hip_runtime.h>
#include <stdint.h>

// AutoRegressiveModel: 47 outer x 512 inner sequential LSTM steps (mid=256).
// Bernoulli sampling bit-matches JAX threefry2x32 (partitionable mode).
//
// R4 structure: 17 blocks x 256 threads.
//   blocks 0..15 : LSTM workers, 4 AUTONOMOUS waves each (no __syncthreads in
//                  the step loop). Wave wv owns h[blk*16+wv*4 .. +4): 16 gate
//                  rows x 256 cols, 64 W_hh weights per lane in VGPRs.
//                  Per step: poll 4 contiguous tagged h words per lane
//                  (2-deep pipelined, FMA burn interleaved for DVFS), stage
//                  into bank-padded wave-private LDS (quarter stride 72 words
//                  -> conflict-free b128 reads), 64-FMA matvec, 2 shfl_xor
//                  q-reduction, 3 shfl gate gather, fast exp2/rcp activations.
//   block 16     : init + sampler (threefry RNG, logprob/entropy, obs feed).
// Heaters removed (R3: no clock benefit). Burn happens on worker CUs instead.

#define MID      256
#define NOUT     48
#define NSEQ     512
#define NOUTER   47
#define NSTEP    (NOUTER * NSEQ)   // 24064
#define NWRK     16
#define SAMP_BLK 16
#define MAGIC_V  0x1234ABCDu
#define LOG2E    1.4426950408889634f

#define AL_RELAX(p)    __hip_atomic_load((p), __ATOMIC_RELAXED, __HIP_MEMORY_SCOPE_AGENT)
#define AL_ACQ(p)      __hip_atomic_load((p), __ATOMIC_ACQUIRE, __HIP_MEMORY_SCOPE_AGENT)
#define AS_RELAX(p, v) __hip_atomic_store((p), (v), __ATOMIC_RELAXED, __HIP_MEMORY_SCOPE_AGENT)
#define AS_REL(p, v)   __hip_atomic_store((p), (v), __ATOMIC_RELEASE, __HIP_MEMORY_SCOPE_AGENT)

__device__ __forceinline__ uint32_t rotl32(uint32_t x, int d) {
  return (x << d) | (x >> (32 - d));
}

// Exact JAX threefry2x32 (20 rounds).
__device__ __forceinline__ void threefry2x32(uint32_t k0, uint32_t k1,
                                             uint32_t x0, uint32_t x1,
                                             uint32_t& o0, uint32_t& o1) {
  uint32_t ks2 = k0 ^ k1 ^ 0x1BD11BDAu;
  uint32_t v0 = x0 + k0, v1 = x1 + k1;
#define TF_R(r) { v0 += v1; v1 = rotl32(v1, r); v1 ^= v0; }
  TF_R(13) TF_R(15) TF_R(26) TF_R(6)
  v0 += k1;  v1 += ks2 + 1u;
  TF_R(17) TF_R(29) TF_R(16) TF_R(24)
  v0 += ks2; v1 += k0 + 2u;
  TF_R(13) TF_R(15) TF_R(26) TF_R(6)
  v0 += k0;  v1 += k1 + 3u;
  TF_R(17) TF_R(29) TF_R(16) TF_R(24)
  v0 += k1;  v1 += ks2 + 4u;
  TF_R(13) TF_R(15) TF_R(26) TF_R(6)
  v0 += ks2; v1 += k0 + 5u;
#undef TF_R
  o0 = v0; o1 = v1;
}

__device__ __forceinline__ float sigf(float x) { return 1.0f / (1.0f + expf(-x)); }

__device__ __forceinline__ uint64_t packht(float h, uint32_t tag) {
  return ((uint64_t)tag << 32) | (uint64_t)__float_as_uint(h);
}

__global__ __launch_bounds__(256, 1)
void arlstm_kernel(const float* __restrict__ W_ih, const float* __restrict__ W_hh,
                   const float* __restrict__ b_ih, const float* __restrict__ b_hh,
                   const float* __restrict__ W_out, const float* __restrict__ b_out,
                   float* __restrict__ out, uint64_t* __restrict__ ws) {
  // ws layout (u64 units):
  uint64_t* h_hist = ws;                                  // [512][256] tagged
  float*    obsbuf = (float*)(ws + 512 * 256);            // [2][512][2]
  uint32_t* p_prog = (uint32_t*)(obsbuf + 2 * 512 * 2);   // [4] sampler progress
  uint32_t* magic  = p_prog + 16;
  float*    sink   = (float*)(p_prog + 32);               // burn sink

  const int tid = threadIdx.x;
  const int blk = blockIdx.x;

  __shared__ float hst[4 * 288];        // worker: 4 waves x (4 quarters x 72)
  __shared__ float lp_acc[512];
  __shared__ float ent_acc[512];
  __shared__ float red[256];

  if (blk == SAMP_BLK) {
    // ----------------------- init + sampler block -----------------------
    AS_RELAX(&h_hist[tid], 0ull);     // slot 0 = h_0 = 0, tag 0
    if (tid < 16) AS_RELAX(&p_prog[tid], 0u);
    out[(tid)       * NOUT] = 0.0f;   // samples column 0 = zeros
    out[(tid + 256) * NOUT] = 0.0f;
    lp_acc[tid] = 0.0f;  lp_acc[tid + 256] = 0.0f;
    ent_acc[tid] = 0.0f; ent_acc[tid + 256] = 0.0f;
    __threadfence();
    __syncthreads();
    if (tid == 0) AS_REL(magic, MAGIC_V);

    const int w    = tid >> 6;   // wave 0..3 handles steps s with (s-1)&3 == w
    const int lane = tid & 63;
    const float wo0 = W_out[lane * 4 + 0], wo1 = W_out[lane * 4 + 1];
    const float wo2 = W_out[lane * 4 + 2], wo3 = W_out[lane * 4 + 3];
    const float bo = b_out[0];
    float z0 = (float)tid + 1.1f, z1 = z0 + 0.7f;
    const float ca = 1.0000001f, cb = 1e-7f;

    for (int s = w + 1; s <= NSTEP; s += 4) {
      const int k = (s - 1) >> 9;
      const int t = (s - 1) & 511;
      uint64_t* src = h_hist + (uint64_t)(s & 511) * 256 + lane * 4;
      uint64_t v0, v1, v2, v3;
      for (;;) {
        v0 = AL_RELAX(src + 0);
        v1 = AL_RELAX(src + 1);
        v2 = AL_RELAX(src + 2);
        v3 = AL_RELAX(src + 3);
        z0 = __builtin_fmaf(z0, ca, cb); z1 = __builtin_fmaf(z1, ca, cb);
        int ok = ((uint32_t)(v0 >> 32) == (uint32_t)s) &
                 ((uint32_t)(v1 >> 32) == (uint32_t)s) &
                 ((uint32_t)(v2 >> 32) == (uint32_t)s) &
                 ((uint32_t)(v3 >> 32) == (uint32_t)s);
        if (__all(ok)) break;
      }
      float zp = fmaf(__uint_as_float((uint32_t)v0), wo0,
                 fmaf(__uint_as_float((uint32_t)v1), wo1,
                 fmaf(__uint_as_float((uint32_t)v2), wo2,
                      __uint_as_float((uint32_t)v3) * wo3)));
      zp += __shfl_xor(zp, 1);
      zp += __shfl_xor(zp, 2);
      zp += __shfl_xor(zp, 4);
      zp += __shfl_xor(zp, 8);
      zp += __shfl_xor(zp, 16);
      zp += __shfl_xor(zp, 32);
      const float p = sigf(zp + bo);

      // JAX partitionable threefry: key_k = tf((0,42),(0,k)); bits = xor of
      // tf(key_k,(0,t)); u = bitcast((bits>>9)|0x3f800000)-1; sample = u < p.
      uint32_t ka, kb, c1, c2;
      threefry2x32(0u, 42u, 0u, (uint32_t)k, ka, kb);
      threefry2x32(ka, kb, 0u, (uint32_t)t, c1, c2);
      const uint32_t bits = c1 ^ c2;
      const float u = __uint_as_float((bits >> 9) | 0x3f800000u) - 1.0f;
      const float smp = (u < p) ? 1.0f : 0.0f;

      if (lane == 0) {
        uint32_t* ob = (uint32_t*)(obsbuf + ((k + 1) & 1) * (512 * 2) + t * 2);
        AS_RELAX(&ob[0], __float_as_uint(smp));
        AS_RELAX(&ob[1], __float_as_uint(p));
        AS_REL(&p_prog[w], (uint32_t)s);
        out[t * NOUT + (k + 1)] = smp;
        const float lg = logf(p), lg1 = log1pf(-p);
        lp_acc[t]  += (smp > 0.5f) ? lg : lg1;
        ent_acc[t] -= (p * lg + (1.0f - p) * lg1);
      }
    }
    __syncthreads();
    // final outputs: logprobs (centered), entropies (mean over 47)
    red[tid] = lp_acc[tid] + lp_acc[tid + 256];
    __syncthreads();
    for (int off = 128; off > 0; off >>= 1) {
      if (tid < off) red[tid] += red[tid + off];
      __syncthreads();
    }
    const float mean = red[0] * (1.0f / 512.0f);
    out[24576 + tid]        = lp_acc[tid]        - mean;
    out[24576 + 256 + tid]  = lp_acc[tid + 256]  - mean;
    out[25088 + tid]        = ent_acc[tid]       * (1.0f / 47.0f);
    out[25088 + 256 + tid]  = ent_acc[tid + 256] * (1.0f / 47.0f);
    if (__float_as_uint(z0 + z1) == 0xDEADBEEFu) sink[256] = z0;
    return;
  }

  // ----------------------------- LSTM worker -----------------------------
  // 4 autonomous waves; wave wv owns h[blk*16 + wv*4 .. +4).
  const int wv = tid >> 6;
  const int l  = tid & 63;
  const int q  = l & 3;                  // column quarter
  const int rr = l >> 2;                 // 0..15: gate g=rr>>2, elem jj=rr&3
  const int g  = rr >> 2;
  const int jj = rr & 3;
  const int row = g * 256 + blk * 16 + wv * 4 + jj;

  float4 wf[16];
#pragma unroll
  for (int i = 0; i < 16; ++i)
    wf[i] = ((const float4*)(W_hh + (uint64_t)row * 256 + q * 64))[i];

  const float bb  = b_ih[row] + b_hh[row];
  const float wx0 = W_ih[row * 2 + 0];
  const float wx1 = W_ih[row * 2 + 1];
  const float mconst = (g == 2) ? (-2.0f * LOG2E) : (-LOG2E);
  const float ml     = (g == 2) ? 2.0f : 1.0f;
  const float ad     = (g == 2) ? -1.0f : 0.0f;

  // LDS addresses (words). Quarter stride 72 (=288B, 16B-aligned, bank shift 8)
  // -> b128 reads of the 4 quarters hit disjoint banks; writes are piecewise
  // stride-1 (2 lanes/bank = free).
  const int wrt = wv * 288 + (l >> 4) * 72 + 4 * (l & 15);  // stage 4 floats
  const int rd  = wv * 288 + q * 72;                        // read base

  float z0 = (float)tid + 1.1f, z1 = z0 + 0.7f, z2 = z0 + 1.3f, z3 = z0 + 2.9f;
  const float ca = 1.0000001f, cb = 1e-7f;

  while (AL_ACQ(magic) != MAGIC_V) {}

  float c_st = 0.0f;                     // live on lanes l<16 (x4 redundant)
  const int hidx = blk * 16 + wv * 4 + jj;

  for (int s = 1; s <= NSTEP; ++s) {
    const int k = (s - 1) >> 9;
    const int t = (s - 1) & 511;

    float sxf = 0.0f, pxf = 0.0f;        // lane 63 carries obs
    if (l == 63 && k > 0) {
      const uint32_t X = (uint32_t)((k - 1) * 512 + t + 1);
      while (AL_ACQ(&p_prog[t & 3]) < X) {}
      uint32_t* ob = (uint32_t*)(obsbuf + (k & 1) * (512 * 2) + t * 2);
      sxf = __uint_as_float(AL_RELAX(&ob[0]));
      pxf = __uint_as_float(AL_RELAX(&ob[1]));
    }

    // ---- poll own 4 tagged words of h_{s-1} (2-deep pipelined + burn) ----
    uint64_t* src = h_hist + (uint64_t)((s - 1) & 511) * 256 + l * 4;
    const uint32_t want = (uint32_t)(s - 1);
    uint64_t a0 = AL_RELAX(src + 0), a1 = AL_RELAX(src + 1);
    uint64_t a2 = AL_RELAX(src + 2), a3 = AL_RELAX(src + 3);
#define TAGS_OK(x0,x1,x2,x3) \
    (((uint32_t)((x0) >> 32) == want) & ((uint32_t)((x1) >> 32) == want) & \
     ((uint32_t)((x2) >> 32) == want) & ((uint32_t)((x3) >> 32) == want))
    if (!__all(TAGS_OK(a0, a1, a2, a3))) {
      uint64_t b0 = AL_RELAX(src + 0), b1 = AL_RELAX(src + 1);
      uint64_t b2 = AL_RELAX(src + 2), b3 = AL_RELAX(src + 3);
      for (;;) {
        z0 = __builtin_fmaf(z0, ca, cb); z1 = __builtin_fmaf(z1, ca, cb);
        z2 = __builtin_fmaf(z2, ca, cb); z3 = __builtin_fmaf(z3, ca, cb);
        if (__all(TAGS_OK(a0, a1, a2, a3))) break;
        a0 = AL_RELAX(src + 0); a1 = AL_RELAX(src + 1);
        a2 = AL_RELAX(src + 2); a3 = AL_RELAX(src + 3);
        z0 = __builtin_fmaf(z0, ca, cb); z1 = __builtin_fmaf(z1, ca, cb);
        z2 = __builtin_fmaf(z2, ca, cb); z3 = __builtin_fmaf(z3, ca, cb);
        if (__all(TAGS_OK(b0, b1, b2, b3))) { a0 = b0; a1 = b1; a2 = b2; a3 = b3; break; }
        b0 = AL_RELAX(src + 0); b1 = AL_RELAX(src + 1);
        b2 = AL_RELAX(src + 2); b3 = AL_RELAX(src + 3);
      }
    }
#undef TAGS_OK

    // ---- stage into wave-private padded LDS (lockstep; lgkm wait only) ----
    *(float4*)&hst[wrt] = make_float4(
        __uint_as_float((uint32_t)a0), __uint_as_float((uint32_t)a1),
        __uint_as_float((uint32_t)a2), __uint_as_float((uint32_t)a3));
    __asm__ volatile("s_waitcnt lgkmcnt(0)" ::: "memory");

    // ---- matvec: 64 cols of quarter q for row rr ----
    float p0 = 0.f, p1 = 0.f, p2 = 0.f, p3 = 0.f;
#pragma unroll
    for (int i = 0; i < 16; ++i) {
      const float4 hv = *(const float4*)&hst[rd + i * 4];
      p0 = fmaf(wf[i].x, hv.x, p0);
      p1 = fmaf(wf[i].y, hv.y, p1);
      p2 = fmaf(wf[i].z, hv.z, p2);
      p3 = fmaf(wf[i].w, hv.w, p3);
    }
    float dot = (p0 + p1) + (p2 + p3);
    dot += __shfl_xor(dot, 1);
    dot += __shfl_xor(dot, 2);           // full row dot on all 4 q-lanes

    const float sx = __shfl(sxf, 63);
    const float px = __shfl(pxf, 63);
    const float gv = dot + fmaf(wx0, sx, fmaf(wx1, px, bb));
    const float e   = __builtin_amdgcn_exp2f(gv * mconst);
    const float y   = __builtin_amdgcn_rcpf(1.0f + e);
    const float act = __builtin_fmaf(ml, y, ad);  // sig for i,f,o; tanh for g

    const float a_f = __shfl(act, (l + 16) & 63);
    const float a_g = __shfl(act, (l + 32) & 63);
    const float a_o = __shfl(act, (l + 48) & 63);

    if (l < 16) {                        // lanes rr<4: act = sig(i) of row jj
      c_st = a_f * c_st + act * a_g;
      const float ec = __builtin_amdgcn_exp2f(c_st * (-2.0f * LOG2E));
      const float yc = __builtin_amdgcn_rcpf(1.0f + ec);
      const float th = __builtin_fmaf(2.0f, yc, -1.0f);
      const float hnew = a_o * th;
      if (q == 0)
        AS_RELAX(&h_hist[(uint64_t)(s & 511) * 256 + hidx], packht(hnew, (uint32_t)s));
    }
  }
  if (__float_as_uint((z0 + z1) + (z2 + z3)) == 0xDEADBEEFu) sink[blk] = z0;
}

extern "C" void kernel_launch(void* const* d_in, const int* in_sizes, int n_in,
                              void* d_out, int out_size, void* d_ws, size_t ws_size,
                              hipStream_t stream) {
  const float* W_ih  = (const float*)d_in[0];
  const float* W_hh  = (const float*)d_in[1];
  const float* b_ih  = (const float*)d_in[2];
  const float* b_hh  = (const float*)d_in[3];
  const float* W_out = (const float*)d_in[4];
  const float* b_out = (const float*)d_in[5];
  float* out = (float*)d_out;
  uint64_t* ws = (uint64_t*)d_ws;

  arlstm_kernel<<<dim3(NWRK + 1), dim3(256), 0, stream>>>(
      W_ih, W_hh, b_ih, b_hh, W_out, b_out, out, ws);
}

// Round 5
// 38433.554 us; speedup vs baseline: 1.0663x; 1.0601x over previous
//
#include <hip/hip_runtime.h>
#include <stdint.h>

// AutoRegressiveModel: 47 outer x 512 inner sequential LSTM steps (mid=256).
// Bernoulli sampling bit-matches JAX threefry2x32 (partitionable mode).
//
// R5 structure: 17 blocks x 256 threads.
//   blocks 0..15 : LSTM workers (R2 skeleton: 1 tagged word polled per thread,
//                  ONE barrier). Wave wv owns h-elems [blk*16+wv*4 .. +4).
//                  Lane l: row-pair rp=l>>3 (gate g=rp>>1, pair jpair=rp&1),
//                  col-chunk ch=l&7 (32 cols). 64 W_hh weights in VGPRs.
//                  Staging LDS double-buffered by step parity, 36-word chunk
//                  stride (conflict-free b128 reads). Reduction: DPP quad_perm
//                  adds (VALU) + one xor-4 swizzle; epilogue gathered intra-
//                  wave via bpermute -> no plds, no 2nd barrier. Raw s_barrier
//                  with lgkmcnt-only wait (no vmcnt drain of h-store).
//   block 16     : init + sampler (threefry RNG, logprob/entropy, obs feed).

#define MID      256
#define NOUT     48
#define NSEQ     512
#define NOUTER   47
#define NSTEP    (NOUTER * NSEQ)   // 24064
#define NWRK     16
#define SAMP_BLK 16
#define MAGIC_V  0x1234ABCDu
#define LOG2E    1.4426950408889634f

#define AL_RELAX(p)    __hip_atomic_load((p), __ATOMIC_RELAXED, __HIP_MEMORY_SCOPE_AGENT)
#define AL_ACQ(p)      __hip_atomic_load((p), __ATOMIC_ACQUIRE, __HIP_MEMORY_SCOPE_AGENT)
#define AS_RELAX(p, v) __hip_atomic_store((p), (v), __ATOMIC_RELAXED, __HIP_MEMORY_SCOPE_AGENT)
#define AS_REL(p, v)   __hip_atomic_store((p), (v), __ATOMIC_RELEASE, __HIP_MEMORY_SCOPE_AGENT)

__device__ __forceinline__ uint32_t rotl32(uint32_t x, int d) {
  return (x << d) | (x >> (32 - d));
}

// Exact JAX threefry2x32 (20 rounds).
__device__ __forceinline__ void threefry2x32(uint32_t k0, uint32_t k1,
                                             uint32_t x0, uint32_t x1,
                                             uint32_t& o0, uint32_t& o1) {
  uint32_t ks2 = k0 ^ k1 ^ 0x1BD11BDAu;
  uint32_t v0 = x0 + k0, v1 = x1 + k1;
#define TF_R(r) { v0 += v1; v1 = rotl32(v1, r); v1 ^= v0; }
  TF_R(13) TF_R(15) TF_R(26) TF_R(6)
  v0 += k1;  v1 += ks2 + 1u;
  TF_R(17) TF_R(29) TF_R(16) TF_R(24)
  v0 += ks2; v1 += k0 + 2u;
  TF_R(13) TF_R(15) TF_R(26) TF_R(6)
  v0 += k0;  v1 += k1 + 3u;
  TF_R(17) TF_R(29) TF_R(16) TF_R(24)
  v0 += k1;  v1 += ks2 + 4u;
  TF_R(13) TF_R(15) TF_R(26) TF_R(6)
  v0 += ks2; v1 += k0 + 5u;
#undef TF_R
  o0 = v0; o1 = v1;
}

__device__ __forceinline__ float sigf(float x) { return 1.0f / (1.0f + expf(-x)); }

// Fast activations (v_exp_f32 + v_rcp_f32), branchless, correct saturation.
__device__ __forceinline__ float fsig(float x) {
  return __builtin_amdgcn_rcpf(1.0f + __builtin_amdgcn_exp2f(x * (-LOG2E)));
}
__device__ __forceinline__ float ftanh(float x) {
  const float e = __builtin_amdgcn_exp2f(x * (-2.0f * LOG2E));
  return __builtin_fmaf(2.0f, __builtin_amdgcn_rcpf(1.0f + e), -1.0f);
}

// x + DPP-permuted x (quad_perm), VALU pipe (no LDS).
template <int CTRL>
__device__ __forceinline__ float dpp_xadd(float x) {
  int v = __builtin_amdgcn_update_dpp(0, __float_as_int(x), CTRL, 0xF, 0xF, true);
  return x + __int_as_float(v);
}

__device__ __forceinline__ uint64_t packht(float h, uint32_t tag) {
  return ((uint64_t)tag << 32) | (uint64_t)__float_as_uint(h);
}

__global__ __launch_bounds__(256, 1)
void arlstm_kernel(const float* __restrict__ W_ih, const float* __restrict__ W_hh,
                   const float* __restrict__ b_ih, const float* __restrict__ b_hh,
                   const float* __restrict__ W_out, const float* __restrict__ b_out,
                   float* __restrict__ out, uint64_t* __restrict__ ws) {
  // ws layout (u64 units):
  uint64_t* h_hist = ws;                                  // [512][256] tagged
  float*    obsbuf = (float*)(ws + 512 * 256);            // [2][512][2]
  uint32_t* p_prog = (uint32_t*)(obsbuf + 2 * 512 * 2);   // [4] sampler progress
  uint32_t* magic  = p_prog + 16;

  const int tid = threadIdx.x;
  const int blk = blockIdx.x;

  __shared__ __align__(16) float hstp[2 * 292];  // worker staging, 2 parity bufs
  __shared__ float obs_s[4];                     // [parity][2]
  __shared__ float lp_acc[512];
  __shared__ float ent_acc[512];
  __shared__ float red[256];

  if (blk == SAMP_BLK) {
    // ----------------------- init + sampler block -----------------------
    AS_RELAX(&h_hist[tid], 0ull);     // slot 0 = h_0 = 0, tag 0
    if (tid < 16) AS_RELAX(&p_prog[tid], 0u);
    out[(tid)       * NOUT] = 0.0f;   // samples column 0 = zeros
    out[(tid + 256) * NOUT] = 0.0f;
    lp_acc[tid] = 0.0f;  lp_acc[tid + 256] = 0.0f;
    ent_acc[tid] = 0.0f; ent_acc[tid + 256] = 0.0f;
    __threadfence();
    __syncthreads();
    if (tid == 0) AS_REL(magic, MAGIC_V);

    const int w    = tid >> 6;   // wave 0..3 handles steps s with (s-1)&3 == w
    const int lane = tid & 63;
    const float wo0 = W_out[lane * 4 + 0], wo1 = W_out[lane * 4 + 1];
    const float wo2 = W_out[lane * 4 + 2], wo3 = W_out[lane * 4 + 3];
    const float bo = b_out[0];

    for (int s = w + 1; s <= NSTEP; s += 4) {
      const int k = (s - 1) >> 9;
      const int t = (s - 1) & 511;
      uint64_t* src = h_hist + (uint64_t)(s & 511) * 256 + lane * 4;
      uint64_t v0, v1, v2, v3;
      for (;;) {
        v0 = AL_RELAX(src + 0);
        v1 = AL_RELAX(src + 1);
        v2 = AL_RELAX(src + 2);
        v3 = AL_RELAX(src + 3);
        int ok = ((uint32_t)(v0 >> 32) == (uint32_t)s) &
                 ((uint32_t)(v1 >> 32) == (uint32_t)s) &
                 ((uint32_t)(v2 >> 32) == (uint32_t)s) &
                 ((uint32_t)(v3 >> 32) == (uint32_t)s);
        if (__all(ok)) break;
      }
      float zp = fmaf(__uint_as_float((uint32_t)v0), wo0,
                 fmaf(__uint_as_float((uint32_t)v1), wo1,
                 fmaf(__uint_as_float((uint32_t)v2), wo2,
                      __uint_as_float((uint32_t)v3) * wo3)));
      zp += __shfl_xor(zp, 1);
      zp += __shfl_xor(zp, 2);
      zp += __shfl_xor(zp, 4);
      zp += __shfl_xor(zp, 8);
      zp += __shfl_xor(zp, 16);
      zp += __shfl_xor(zp, 32);
      const float p = sigf(zp + bo);

      // JAX partitionable threefry: key_k = tf((0,42),(0,k)); bits = xor of
      // tf(key_k,(0,t)); u = bitcast((bits>>9)|0x3f800000)-1; sample = u < p.
      uint32_t ka, kb, c1, c2;
      threefry2x32(0u, 42u, 0u, (uint32_t)k, ka, kb);
      threefry2x32(ka, kb, 0u, (uint32_t)t, c1, c2);
      const uint32_t bits = c1 ^ c2;
      const float u = __uint_as_float((bits >> 9) | 0x3f800000u) - 1.0f;
      const float smp = (u < p) ? 1.0f : 0.0f;

      if (lane == 0) {
        uint32_t* ob = (uint32_t*)(obsbuf + ((k + 1) & 1) * (512 * 2) + t * 2);
        AS_RELAX(&ob[0], __float_as_uint(smp));
        AS_RELAX(&ob[1], __float_as_uint(p));
        AS_REL(&p_prog[w], (uint32_t)s);
        out[t * NOUT + (k + 1)] = smp;
        const float lg = logf(p), lg1 = log1pf(-p);
        lp_acc[t]  += (smp > 0.5f) ? lg : lg1;
        ent_acc[t] -= (p * lg + (1.0f - p) * lg1);
      }
    }
    __syncthreads();
    // final outputs: logprobs (centered), entropies (mean over 47)
    red[tid] = lp_acc[tid] + lp_acc[tid + 256];
    __syncthreads();
    for (int off = 128; off > 0; off >>= 1) {
      if (tid < off) red[tid] += red[tid + off];
      __syncthreads();
    }
    const float mean = red[0] * (1.0f / 512.0f);
    out[24576 + tid]        = lp_acc[tid]        - mean;
    out[24576 + 256 + tid]  = lp_acc[tid + 256]  - mean;
    out[25088 + tid]        = ent_acc[tid]       * (1.0f / 47.0f);
    out[25088 + 256 + tid]  = ent_acc[tid + 256] * (1.0f / 47.0f);
    return;
  }

  // ----------------------------- LSTM worker -----------------------------
  const int wv = tid >> 6;               // wave: owns h-elems [blk*16+wv*4, +4)
  const int l  = tid & 63;
  const int ch = l & 7;                  // 32-col chunk
  const int rp = l >> 3;                 // row-pair: g = rp>>1, jpair = rp&1
  const int g  = rp >> 1;
  const int jpair = rp & 1;
  const int R0 = g * 256 + blk * 16 + wv * 4 + 2 * jpair;   // R1 = R0+1

  float4 w0[8], w1[8];
#pragma unroll
  for (int i = 0; i < 8; ++i) {
    w0[i] = ((const float4*)(W_hh + (uint64_t)R0 * 256 + ch * 32))[i];
    w1[i] = ((const float4*)(W_hh + (uint64_t)(R0 + 1) * 256 + ch * 32))[i];
  }

  // Epilogue constants for elem e = blk*16 + wv*4 + l (lanes l<4).
  float eb[4] = {0, 0, 0, 0}, ew0[4] = {0, 0, 0, 0}, ew1[4] = {0, 0, 0, 0};
  if (l < 4) {
#pragma unroll
    for (int g4 = 0; g4 < 4; ++g4) {
      const int rr = g4 * 256 + blk * 16 + wv * 4 + l;
      eb[g4]  = b_ih[rr] + b_hh[rr];
      ew0[g4] = W_ih[rr * 2 + 0];
      ew1[g4] = W_ih[rr * 2 + 1];
    }
  }

  while (AL_ACQ(magic) != MAGIC_V) {}

  float c_st = 0.0f;                     // lanes l<4 carry c for elem wv*4+l
  const int hidx = blk * 16 + wv * 4 + l;  // store target (l<4)

  for (int s = 1; s <= NSTEP; ++s) {
    const int k = (s - 1) >> 9;
    const int t = (s - 1) & 511;
    const int buf = s & 1;

    // obs for this step (tid 255 = wave 3 lane 63), staged pre-barrier
    if (tid == 255) {
      float sxf = 0.0f, pxf = 0.0f;
      if (k > 0) {
        const uint32_t X = (uint32_t)((k - 1) * 512 + t + 1);
        while (AL_ACQ(&p_prog[t & 3]) < X) {}
        uint32_t* ob = (uint32_t*)(obsbuf + (k & 1) * (512 * 2) + t * 2);
        sxf = __uint_as_float(AL_RELAX(&ob[0]));
        pxf = __uint_as_float(AL_RELAX(&ob[1]));
      }
      obs_s[buf * 2 + 0] = sxf;
      obs_s[buf * 2 + 1] = pxf;
    }

    // ---- poll own tagged word of h_{s-1} (2-deep pipelined) ----
    {
      uint64_t* src = h_hist + (uint64_t)((s - 1) & 511) * 256 + tid;
      const uint32_t want = (uint32_t)(s - 1);
      uint64_t x = AL_RELAX(src);
      if ((uint32_t)(x >> 32) != want) {
        uint64_t y = AL_RELAX(src);
        for (;;) {
          if ((uint32_t)(x >> 32) == want) break;
          x = AL_RELAX(src);
          if ((uint32_t)(y >> 32) == want) { x = y; break; }
          y = AL_RELAX(src);
        }
      }
      // stage h[tid] into parity buffer, 36-word chunk stride
      hstp[buf * 292 + (tid >> 5) * 36 + (tid & 31)] = __uint_as_float((uint32_t)x);
    }
    __asm__ volatile("s_waitcnt lgkmcnt(0)" ::: "memory");
    __builtin_amdgcn_s_barrier();        // no vmcnt drain (h-store stays in flight)

    // ---- matvec: 2 rows x 32 cols (8 conflict-free ds_read_b128) ----
    const float4* hs = (const float4*)&hstp[buf * 292 + ch * 36];
    float a00 = 0.f, a01 = 0.f, a02 = 0.f, a03 = 0.f;
    float a10 = 0.f, a11 = 0.f, a12 = 0.f, a13 = 0.f;
#pragma unroll
    for (int i = 0; i < 8; ++i) {
      const float4 hv = hs[i];
      a00 = fmaf(w0[i].x, hv.x, a00);
      a01 = fmaf(w0[i].y, hv.y, a01);
      a02 = fmaf(w0[i].z, hv.z, a02);
      a03 = fmaf(w0[i].w, hv.w, a03);
      a10 = fmaf(w1[i].x, hv.x, a10);
      a11 = fmaf(w1[i].y, hv.y, a11);
      a12 = fmaf(w1[i].z, hv.z, a12);
      a13 = fmaf(w1[i].w, hv.w, a13);
    }
    float d0 = (a00 + a01) + (a02 + a03);   // row R0 partial (32 cols)
    float d1 = (a10 + a11) + (a12 + a13);   // row R1 partial

    // reduce over ch (8 lanes): xor1/xor2 via DPP quad_perm (VALU), xor4 swizzle
    d0 = dpp_xadd<0xB1>(d0); d1 = dpp_xadd<0xB1>(d1);   // quad_perm [1,0,3,2]
    d0 = dpp_xadd<0x4E>(d0); d1 = dpp_xadd<0x4E>(d1);   // quad_perm [2,3,0,1]
    d0 += __shfl_xor(d0, 4, 64);
    d1 += __shfl_xor(d1, 4, 64);
    // now all lanes with this rp hold full row-dots d0 (row R0), d1 (row R1)

    // ---- gather the 4 gates for elem e = l (valid on lanes l<4) ----
    const int hsel = (l >> 1) & 1;       // e>>1: which row-pair
    const int osel = l & 1;              // e&1: which row within pair
    float G0, G1, G2, G3;
    {
      const float u0 = __shfl(d0, (0 + hsel) * 8, 64);
      const float v0 = __shfl(d1, (0 + hsel) * 8, 64);
      G0 = osel ? v0 : u0;
      const float u1 = __shfl(d0, (2 + hsel) * 8, 64);
      const float v1 = __shfl(d1, (2 + hsel) * 8, 64);
      G1 = osel ? v1 : u1;
      const float u2 = __shfl(d0, (4 + hsel) * 8, 64);
      const float v2 = __shfl(d1, (4 + hsel) * 8, 64);
      G2 = osel ? v2 : u2;
      const float u3 = __shfl(d0, (6 + hsel) * 8, 64);
      const float v3 = __shfl(d1, (6 + hsel) * 8, 64);
      G3 = osel ? v3 : u3;
    }

    // ---- epilogue (lanes l<4 produce this wave's 4 h elements) ----
    const float sx = obs_s[buf * 2 + 0];
    const float px = obs_s[buf * 2 + 1];
    G0 += fmaf(ew0[0], sx, fmaf(ew1[0], px, eb[0]));
    G1 += fmaf(ew0[1], sx, fmaf(ew1[1], px, eb[1]));
    G2 += fmaf(ew0[2], sx, fmaf(ew1[2], px, eb[2]));
    G3 += fmaf(ew0[3], sx, fmaf(ew1[3], px, eb[3]));
    const float gi = fsig(G0);
    const float gf = fsig(G1);
    const float gz = ftanh(G2);
    const float go = fsig(G3);
    c_st = fmaf(gf, c_st, gi * gz);
    const float hnew = go * ftanh(c_st);
    if (l < 4)
      AS_RELAX(&h_hist[(uint64_t)(s & 511) * 256 + hidx],
               packht(hnew, (uint32_t)s));
  }
}

extern "C" void kernel_launch(void* const* d_in, const int* in_sizes, int n_in,
                              void* d_out, int out_size, void* d_ws, size_t ws_size,
                              hipStream_t stream) {
  const float* W_ih  = (const float*)d_in[0];
  const float* W_hh  = (const float*)d_in[1];
  const float* b_ih  = (const float*)d_in[2];
  const float* b_hh  = (const float*)d_in[3];
  const float* W_out = (const float*)d_in[4];
  const float* b_out = (const float*)d_in[5];
  float* out = (float*)d_out;
  uint64_t* ws = (uint64_t*)d_ws;

  arlstm_kernel<<<dim3(NWRK + 1), dim3(256), 0, stream>>>(
      W_ih, W_hh, b_ih, b_hh, W_out, b_out, out, ws);
}

// Round 6
// 36607.120 us; speedup vs baseline: 1.1195x; 1.0499x over previous
//
#include <hip/hip_runtime.h>
#include <stdint.h>

// AutoRegressiveModel: 47 outer x 512 inner sequential LSTM steps (mid=256).
// Bernoulli sampling bit-matches JAX threefry2x32 (partitionable mode).
//
// R6 = R2 skeleton (proven comms: 1 tagged word polled per thread, LDS stage,
// two barriers, wave-0 epilogue, ONE coalesced 16-lane h-store) + 3 deltas:
//  1. matvec 2 rows x 32 cols per lane: 8 ds_read_b128 (2-way alias = free)
//     + one DPP xor1 add (VALU) -> LDS pipe ~410 cyc/step (was ~770).
//  2. raw s_barrier with lgkmcnt(0)-only (no vmcnt drain of in-flight h-store);
//     waves 1-3 start next-step polling while wave 0 does the epilogue.
//  3. 4-deep pipelined poll; obs parity-buffered (fixes R2's latent race).
//
// blocks 0..15 workers; block 16 init + sampler.

#define MID      256
#define NOUT     48
#define NSEQ     512
#define NOUTER   47
#define NSTEP    (NOUTER * NSEQ)   // 24064
#define NWRK     16
#define SAMP_BLK 16
#define MAGIC_V  0x1234ABCDu
#define LOG2E    1.4426950408889634f

#define AL_RELAX(p)    __hip_atomic_load((p), __ATOMIC_RELAXED, __HIP_MEMORY_SCOPE_AGENT)
#define AL_ACQ(p)      __hip_atomic_load((p), __ATOMIC_ACQUIRE, __HIP_MEMORY_SCOPE_AGENT)
#define AS_RELAX(p, v) __hip_atomic_store((p), (v), __ATOMIC_RELAXED, __HIP_MEMORY_SCOPE_AGENT)
#define AS_REL(p, v)   __hip_atomic_store((p), (v), __ATOMIC_RELEASE, __HIP_MEMORY_SCOPE_AGENT)

__device__ __forceinline__ uint32_t rotl32(uint32_t x, int d) {
  return (x << d) | (x >> (32 - d));
}

// Exact JAX threefry2x32 (20 rounds).
__device__ __forceinline__ void threefry2x32(uint32_t k0, uint32_t k1,
                                             uint32_t x0, uint32_t x1,
                                             uint32_t& o0, uint32_t& o1) {
  uint32_t ks2 = k0 ^ k1 ^ 0x1BD11BDAu;
  uint32_t v0 = x0 + k0, v1 = x1 + k1;
#define TF_R(r) { v0 += v1; v1 = rotl32(v1, r); v1 ^= v0; }
  TF_R(13) TF_R(15) TF_R(26) TF_R(6)
  v0 += k1;  v1 += ks2 + 1u;
  TF_R(17) TF_R(29) TF_R(16) TF_R(24)
  v0 += ks2; v1 += k0 + 2u;
  TF_R(13) TF_R(15) TF_R(26) TF_R(6)
  v0 += k0;  v1 += k1 + 3u;
  TF_R(17) TF_R(29) TF_R(16) TF_R(24)
  v0 += k1;  v1 += ks2 + 4u;
  TF_R(13) TF_R(15) TF_R(26) TF_R(6)
  v0 += ks2; v1 += k0 + 5u;
#undef TF_R
  o0 = v0; o1 = v1;
}

__device__ __forceinline__ float sigf(float x) { return 1.0f / (1.0f + expf(-x)); }

// x + DPP quad_perm-permuted x (VALU pipe, no LDS).
template <int CTRL>
__device__ __forceinline__ float dpp_xadd(float x) {
  int v = __builtin_amdgcn_update_dpp(0, __float_as_int(x), CTRL, 0xF, 0xF, true);
  return x + __int_as_float(v);
}

__device__ __forceinline__ uint64_t packht(float h, uint32_t tag) {
  return ((uint64_t)tag << 32) | (uint64_t)__float_as_uint(h);
}

#define BARRIER_LGKM() __asm__ volatile("s_waitcnt lgkmcnt(0)\ns_barrier" ::: "memory")

__global__ __launch_bounds__(256, 1)
void arlstm_kernel(const float* __restrict__ W_ih, const float* __restrict__ W_hh,
                   const float* __restrict__ b_ih, const float* __restrict__ b_hh,
                   const float* __restrict__ W_out, const float* __restrict__ b_out,
                   float* __restrict__ out, uint64_t* __restrict__ ws) {
  // ws layout (u64 units):
  uint64_t* h_hist = ws;                                  // [512][256] tagged
  float*    obsbuf = (float*)(ws + 512 * 256);            // [2][512][2]
  uint32_t* p_prog = (uint32_t*)(obsbuf + 2 * 512 * 2);   // [4] sampler progress
  uint32_t* magic  = p_prog + 16;

  const int tid = threadIdx.x;
  const int blk = blockIdx.x;

  __shared__ __align__(16) float hstage[256];
  __shared__ float plds[4][64];                  // [quarter][local row]
  __shared__ float obs_s[4];                     // [parity][2]
  __shared__ float lp_acc[512];
  __shared__ float ent_acc[512];
  __shared__ float red[256];

  if (blk == SAMP_BLK) {
    // ----------------------- init + sampler block -----------------------
    AS_RELAX(&h_hist[tid], 0ull);     // slot 0 = h_0 = 0, tag 0
    if (tid < 16) AS_RELAX(&p_prog[tid], 0u);
    out[(tid)       * NOUT] = 0.0f;   // samples column 0 = zeros
    out[(tid + 256) * NOUT] = 0.0f;
    lp_acc[tid] = 0.0f;  lp_acc[tid + 256] = 0.0f;
    ent_acc[tid] = 0.0f; ent_acc[tid + 256] = 0.0f;
    __threadfence();
    __syncthreads();
    if (tid == 0) AS_REL(magic, MAGIC_V);

    const int w    = tid >> 6;   // wave 0..3 handles steps s with (s-1)&3 == w
    const int lane = tid & 63;
    const float wo0 = W_out[lane * 4 + 0], wo1 = W_out[lane * 4 + 1];
    const float wo2 = W_out[lane * 4 + 2], wo3 = W_out[lane * 4 + 3];
    const float bo = b_out[0];

    for (int s = w + 1; s <= NSTEP; s += 4) {
      const int k = (s - 1) >> 9;
      const int t = (s - 1) & 511;
      uint64_t* src = h_hist + (uint64_t)(s & 511) * 256 + lane * 4;
      uint64_t v0, v1, v2, v3;
      for (;;) {
        v0 = AL_RELAX(src + 0);
        v1 = AL_RELAX(src + 1);
        v2 = AL_RELAX(src + 2);
        v3 = AL_RELAX(src + 3);
        int ok = ((uint32_t)(v0 >> 32) == (uint32_t)s) &
                 ((uint32_t)(v1 >> 32) == (uint32_t)s) &
                 ((uint32_t)(v2 >> 32) == (uint32_t)s) &
                 ((uint32_t)(v3 >> 32) == (uint32_t)s);
        if (__all(ok)) break;
      }
      float zp = fmaf(__uint_as_float((uint32_t)v0), wo0,
                 fmaf(__uint_as_float((uint32_t)v1), wo1,
                 fmaf(__uint_as_float((uint32_t)v2), wo2,
                      __uint_as_float((uint32_t)v3) * wo3)));
      zp += __shfl_xor(zp, 1);
      zp += __shfl_xor(zp, 2);
      zp += __shfl_xor(zp, 4);
      zp += __shfl_xor(zp, 8);
      zp += __shfl_xor(zp, 16);
      zp += __shfl_xor(zp, 32);
      const float p = sigf(zp + bo);

      // JAX partitionable threefry: key_k = tf((0,42),(0,k)); bits = xor of
      // tf(key_k,(0,t)); u = bitcast((bits>>9)|0x3f800000)-1; sample = u < p.
      uint32_t ka, kb, c1, c2;
      threefry2x32(0u, 42u, 0u, (uint32_t)k, ka, kb);
      threefry2x32(ka, kb, 0u, (uint32_t)t, c1, c2);
      const uint32_t bits = c1 ^ c2;
      const float u = __uint_as_float((bits >> 9) | 0x3f800000u) - 1.0f;
      const float smp = (u < p) ? 1.0f : 0.0f;

      if (lane == 0) {
        uint32_t* ob = (uint32_t*)(obsbuf + ((k + 1) & 1) * (512 * 2) + t * 2);
        AS_RELAX(&ob[0], __float_as_uint(smp));
        AS_RELAX(&ob[1], __float_as_uint(p));
        AS_REL(&p_prog[w], (uint32_t)s);
        out[t * NOUT + (k + 1)] = smp;
        const float lg = logf(p), lg1 = log1pf(-p);
        lp_acc[t]  += (smp > 0.5f) ? lg : lg1;
        ent_acc[t] -= (p * lg + (1.0f - p) * lg1);
      }
    }
    __syncthreads();
    // final outputs: logprobs (centered), entropies (mean over 47)
    red[tid] = lp_acc[tid] + lp_acc[tid + 256];
    __syncthreads();
    for (int off = 128; off > 0; off >>= 1) {
      if (tid < off) red[tid] += red[tid + off];
      __syncthreads();
    }
    const float mean = red[0] * (1.0f / 512.0f);
    out[24576 + tid]        = lp_acc[tid]        - mean;
    out[24576 + 256 + tid]  = lp_acc[tid + 256]  - mean;
    out[25088 + tid]        = ent_acc[tid]       * (1.0f / 47.0f);
    out[25088 + 256 + tid]  = ent_acc[tid + 256] * (1.0f / 47.0f);
    return;
  }

  // ----------------------------- LSTM worker -----------------------------
  const int wv = tid >> 6;               // column quarter (cols [64wv, 64wv+64))
  const int l  = tid & 63;
  const int hf = l & 1;                  // 32-col half within the quarter
  const int lr = l & ~1;                 // local row pair {lr, lr+1}
  const int gr0 = ((lr)     >> 4) * 256 + blk * 16 + ((lr)     & 15);
  const int gr1 = ((lr + 1) >> 4) * 256 + blk * 16 + ((lr + 1) & 15);

  float4 w0[8], w1[8];
#pragma unroll
  for (int i = 0; i < 8; ++i) {
    w0[i] = ((const float4*)(W_hh + (uint64_t)gr0 * 256 + wv * 64 + hf * 32))[i];
    w1[i] = ((const float4*)(W_hh + (uint64_t)gr1 * 256 + wv * 64 + hf * 32))[i];
  }

  // Epilogue constants (wave 0, one gate-row per lane: lane = g*16 + j).
  float bb = 0.f, wx0 = 0.f, wx1 = 0.f, mconst = 0.f, ml = 0.f, ad = 0.f;
  if (tid < 64) {
    const int g4 = tid >> 4;
    const int rr = g4 * 256 + blk * 16 + (tid & 15);
    bb  = b_ih[rr] + b_hh[rr];
    wx0 = W_ih[rr * 2 + 0];
    wx1 = W_ih[rr * 2 + 1];
    mconst = (g4 == 2) ? (-2.0f * LOG2E) : (-LOG2E);  // act = ml*sig-form + ad
    ml     = (g4 == 2) ? 2.0f : 1.0f;
    ad     = (g4 == 2) ? -1.0f : 0.0f;
  }

  while (AL_ACQ(magic) != MAGIC_V) {}

  float c_st = 0.0f;                     // cell state (lanes tid<16)
  const int jglob = blk * 16 + (tid & 15);

  for (int s = 1; s <= NSTEP; ++s) {
    const int k = (s - 1) >> 9;
    const int t = (s - 1) & 511;
    const int par = s & 1;

    // obs for this step (tid 255 = wave 3 lane 63), parity-buffered
    if (tid == 255) {
      float sxf = 0.0f, pxf = 0.0f;
      if (k > 0) {
        const uint32_t X = (uint32_t)((k - 1) * 512 + t + 1);
        while (AL_ACQ(&p_prog[t & 3]) < X) {}
        uint32_t* ob = (uint32_t*)(obsbuf + (k & 1) * (512 * 2) + t * 2);
        sxf = __uint_as_float(AL_RELAX(&ob[0]));
        pxf = __uint_as_float(AL_RELAX(&ob[1]));
      }
      obs_s[par * 2 + 0] = sxf;
      obs_s[par * 2 + 1] = pxf;
    }

    // ---- poll own tagged word of h_{s-1} (4-deep pipelined) ----
    {
      uint64_t* src = h_hist + (uint64_t)((s - 1) & 511) * 256 + tid;
      const uint32_t want = (uint32_t)(s - 1);
      uint64_t x0 = AL_RELAX(src), x1 = AL_RELAX(src);
      uint64_t x2 = AL_RELAX(src), x3 = AL_RELAX(src);
      uint64_t v;
      for (;;) {
        if ((uint32_t)(x0 >> 32) == want) { v = x0; break; }
        x0 = AL_RELAX(src);
        if ((uint32_t)(x1 >> 32) == want) { v = x1; break; }
        x1 = AL_RELAX(src);
        if ((uint32_t)(x2 >> 32) == want) { v = x2; break; }
        x2 = AL_RELAX(src);
        if ((uint32_t)(x3 >> 32) == want) { v = x3; break; }
        x3 = AL_RELAX(src);
      }
      hstage[tid] = __uint_as_float((uint32_t)v);
    }
    BARRIER_LGKM();                      // no vmcnt drain (h-store in flight)

    // ---- matvec: 2 rows x 32 cols (8 b128, 2-way alias = free) ----
    const float4* hs = (const float4*)(hstage + wv * 64 + hf * 32);
    float a00 = 0.f, a01 = 0.f, a02 = 0.f, a03 = 0.f;
    float a10 = 0.f, a11 = 0.f, a12 = 0.f, a13 = 0.f;
#pragma unroll
    for (int i = 0; i < 8; ++i) {
      const float4 hv = hs[i];
      a00 = fmaf(w0[i].x, hv.x, a00);
      a01 = fmaf(w0[i].y, hv.y, a01);
      a02 = fmaf(w0[i].z, hv.z, a02);
      a03 = fmaf(w0[i].w, hv.w, a03);
      a10 = fmaf(w1[i].x, hv.x, a10);
      a11 = fmaf(w1[i].y, hv.y, a11);
      a12 = fmaf(w1[i].z, hv.z, a12);
      a13 = fmaf(w1[i].w, hv.w, a13);
    }
    float d0 = (a00 + a01) + (a02 + a03);   // row lr,   this 32-col half
    float d1 = (a10 + a11) + (a12 + a13);   // row lr+1, this 32-col half
    d0 = dpp_xadd<0xB1>(d0);                // + neighbor half -> full quarter dot
    d1 = dpp_xadd<0xB1>(d1);
    plds[wv][l] = hf ? d1 : d0;             // row l's quarter-dot (stride-1 write)
    BARRIER_LGKM();

    // ---- epilogue on wave 0 (one gate-row per lane) ----
    if (tid < 64) {
      const float sx = obs_s[par * 2 + 0];
      const float px = obs_s[par * 2 + 1];
      const float gv = ((plds[0][tid] + plds[1][tid]) +
                        (plds[2][tid] + plds[3][tid])) +
                       fmaf(wx0, sx, fmaf(wx1, px, bb));
      const float e   = __builtin_amdgcn_exp2f(gv * mconst);
      const float y   = __builtin_amdgcn_rcpf(1.0f + e);
      const float act = __builtin_fmaf(ml, y, ad);  // sig for i,f,o; tanh for g
      const int j = tid & 15;
      const float a_f = __shfl(act, j + 16, 64);
      const float a_g = __shfl(act, j + 32, 64);
      const float a_o = __shfl(act, j + 48, 64);
      if (tid < 16) {                    // lanes 0..15: act = sig(i)
        c_st = fmaf(a_f, c_st, act * a_g);
        const float ec = __builtin_amdgcn_exp2f(c_st * (-2.0f * LOG2E));
        const float yc = __builtin_amdgcn_rcpf(1.0f + ec);
        const float th = __builtin_fmaf(2.0f, yc, -1.0f);
        const float hnew = a_o * th;
        AS_RELAX(&h_hist[(uint64_t)(s & 511) * 256 + jglob],
                 packht(hnew, (uint32_t)s));
      }
    }
  }
}

extern "C" void kernel_launch(void* const* d_in, const int* in_sizes, int n_in,
                              void* d_out, int out_size, void* d_ws, size_t ws_size,
                              hipStream_t stream) {
  const float* W_ih  = (const float*)d_in[0];
  const float* W_hh  = (const float*)d_in[1];
  const float* b_ih  = (const float*)d_in[2];
  const float* b_hh  = (const float*)d_in[3];
  const float* W_out = (const float*)d_in[4];
  const float* b_out = (const float*)d_in[5];
  float* out = (float*)d_out;
  uint64_t* ws = (uint64_t*)d_ws;

  arlstm_kernel<<<dim3(NWRK + 1), dim3(256), 0, stream>>>(
      W_ih, W_hh, b_ih, b_hh, W_out, b_out, out, ws);
}

// Round 7
// 31878.110 us; speedup vs baseline: 1.2855x; 1.1483x over previous
//
#include <hip/hip_runtime.h>
#include <stdint.h>

// AutoRegressiveModel: 47 outer x 512 inner sequential LSTM steps (mid=256).
// Bernoulli sampling bit-matches JAX threefry2x32 (partitionable mode).
//
// R7 = R2 (31.8 ms, fastest so far) + exactly TWO deltas:
//  1. barrier1: raw s_barrier with lgkmcnt(0)-only wait. R2's __syncthreads
//     emitted s_waitcnt vmcnt(0), draining the in-flight 2nd pipelined poll
//     load (~RTT for the last-detecting thread, every step). The detected h
//     value is already consumed into LDS; the stale load is discardable.
//  2. obs double-buffered by step parity (closes R2's latent race between
//     wave0's epilogue read and tid255's next-step overwrite).
// Everything else (1-word 2-deep poll, broadcast 16x ds_read_b128 matvec,
// plds, __syncthreads barrier2, 64-lane epilogue, 16-lane coalesced h-store)
// is byte-for-byte R2 — the proven-fastest structure (R3-R6 all regressed).
//
// blocks 0..15 workers; block 16 init + sampler.

#define MID      256
#define NOUT     48
#define NSEQ     512
#define NOUTER   47
#define NSTEP    (NOUTER * NSEQ)   // 24064
#define NWRK     16
#define SAMP_BLK 16
#define MAGIC_V  0x1234ABCDu
#define LOG2E    1.4426950408889634f

#define AL_RELAX(p)    __hip_atomic_load((p), __ATOMIC_RELAXED, __HIP_MEMORY_SCOPE_AGENT)
#define AL_ACQ(p)      __hip_atomic_load((p), __ATOMIC_ACQUIRE, __HIP_MEMORY_SCOPE_AGENT)
#define AS_RELAX(p, v) __hip_atomic_store((p), (v), __ATOMIC_RELAXED, __HIP_MEMORY_SCOPE_AGENT)
#define AS_REL(p, v)   __hip_atomic_store((p), (v), __ATOMIC_RELEASE, __HIP_MEMORY_SCOPE_AGENT)

// Barrier with LDS-only drain (leaves global loads/stores in flight).
#define BARRIER_LGKM() __asm__ volatile("s_waitcnt lgkmcnt(0)\ns_barrier" ::: "memory")

__device__ __forceinline__ uint32_t rotl32(uint32_t x, int d) {
  return (x << d) | (x >> (32 - d));
}

// Exact JAX threefry2x32 (20 rounds).
__device__ __forceinline__ void threefry2x32(uint32_t k0, uint32_t k1,
                                             uint32_t x0, uint32_t x1,
                                             uint32_t& o0, uint32_t& o1) {
  uint32_t ks2 = k0 ^ k1 ^ 0x1BD11BDAu;
  uint32_t v0 = x0 + k0, v1 = x1 + k1;
#define TF_R(r) { v0 += v1; v1 = rotl32(v1, r); v1 ^= v0; }
  TF_R(13) TF_R(15) TF_R(26) TF_R(6)
  v0 += k1;  v1 += ks2 + 1u;
  TF_R(17) TF_R(29) TF_R(16) TF_R(24)
  v0 += ks2; v1 += k0 + 2u;
  TF_R(13) TF_R(15) TF_R(26) TF_R(6)
  v0 += k0;  v1 += k1 + 3u;
  TF_R(17) TF_R(29) TF_R(16) TF_R(24)
  v0 += k1;  v1 += ks2 + 4u;
  TF_R(13) TF_R(15) TF_R(26) TF_R(6)
  v0 += ks2; v1 += k0 + 5u;
#undef TF_R
  o0 = v0; o1 = v1;
}

// Accurate sigmoid for the sampler (off critical path).
__device__ __forceinline__ float sigf(float x) { return 1.0f / (1.0f + expf(-x)); }

__device__ __forceinline__ uint64_t packht(float h, uint32_t tag) {
  return ((uint64_t)tag << 32) | (uint64_t)__float_as_uint(h);
}

__global__ __launch_bounds__(256, 1)
void arlstm_kernel(const float* __restrict__ W_ih, const float* __restrict__ W_hh,
                   const float* __restrict__ b_ih, const float* __restrict__ b_hh,
                   const float* __restrict__ W_out, const float* __restrict__ b_out,
                   float* __restrict__ out, uint64_t* __restrict__ ws) {
  // ws layout (u64 units):
  uint64_t* h_hist = ws;                                  // [512][256] tagged
  float*    obsbuf = (float*)(ws + 512 * 256);            // [2][512][2]
  uint32_t* p_prog = (uint32_t*)(obsbuf + 2 * 512 * 2);   // [4] sampler progress
  uint32_t* magic  = p_prog + 16;

  const int tid = threadIdx.x;
  const int blk = blockIdx.x;

  __shared__ __align__(16) float hstage[256];
  __shared__ float plds[4][64];
  __shared__ float obs_s[4];                     // [parity][2]
  __shared__ float lp_acc[512];
  __shared__ float ent_acc[512];
  __shared__ float red[256];

  if (blk == SAMP_BLK) {
    // ----------------------- init + sampler block -----------------------
    AS_RELAX(&h_hist[tid], 0ull);     // slot 0 = h_0 = 0, tag 0
    if (tid < 16) AS_RELAX(&p_prog[tid], 0u);
    out[(tid)       * NOUT] = 0.0f;   // samples column 0 = zeros
    out[(tid + 256) * NOUT] = 0.0f;
    lp_acc[tid] = 0.0f;  lp_acc[tid + 256] = 0.0f;
    ent_acc[tid] = 0.0f; ent_acc[tid + 256] = 0.0f;
    __threadfence();
    __syncthreads();
    if (tid == 0) AS_REL(magic, MAGIC_V);

    const int w    = tid >> 6;   // wave 0..3 handles steps s with (s-1)&3 == w
    const int lane = tid & 63;
    const float wo0 = W_out[lane * 4 + 0], wo1 = W_out[lane * 4 + 1];
    const float wo2 = W_out[lane * 4 + 2], wo3 = W_out[lane * 4 + 3];
    const float bo = b_out[0];

    for (int s = w + 1; s <= NSTEP; s += 4) {
      const int k = (s - 1) >> 9;
      const int t = (s - 1) & 511;
      uint64_t* src = h_hist + (uint64_t)(s & 511) * 256 + lane * 4;
      uint64_t v0, v1, v2, v3;
      for (;;) {
        v0 = AL_RELAX(src + 0);
        v1 = AL_RELAX(src + 1);
        v2 = AL_RELAX(src + 2);
        v3 = AL_RELAX(src + 3);
        int ok = ((uint32_t)(v0 >> 32) == (uint32_t)s) &
                 ((uint32_t)(v1 >> 32) == (uint32_t)s) &
                 ((uint32_t)(v2 >> 32) == (uint32_t)s) &
                 ((uint32_t)(v3 >> 32) == (uint32_t)s);
        if (__all(ok)) break;
      }
      float zp = fmaf(__uint_as_float((uint32_t)v0), wo0,
                 fmaf(__uint_as_float((uint32_t)v1), wo1,
                 fmaf(__uint_as_float((uint32_t)v2), wo2,
                      __uint_as_float((uint32_t)v3) * wo3)));
      zp += __shfl_xor(zp, 1);
      zp += __shfl_xor(zp, 2);
      zp += __shfl_xor(zp, 4);
      zp += __shfl_xor(zp, 8);
      zp += __shfl_xor(zp, 16);
      zp += __shfl_xor(zp, 32);
      const float p = sigf(zp + bo);

      // JAX partitionable threefry: key_k = tf((0,42),(0,k)); bits = xor of
      // tf(key_k,(0,t)); u = bitcast((bits>>9)|0x3f800000)-1; sample = u < p.
      uint32_t ka, kb, c1, c2;
      threefry2x32(0u, 42u, 0u, (uint32_t)k, ka, kb);
      threefry2x32(ka, kb, 0u, (uint32_t)t, c1, c2);
      const uint32_t bits = c1 ^ c2;
      const float u = __uint_as_float((bits >> 9) | 0x3f800000u) - 1.0f;
      const float smp = (u < p) ? 1.0f : 0.0f;

      if (lane == 0) {
        uint32_t* ob = (uint32_t*)(obsbuf + ((k + 1) & 1) * (512 * 2) + t * 2);
        AS_RELAX(&ob[0], __float_as_uint(smp));
        AS_RELAX(&ob[1], __float_as_uint(p));
        AS_REL(&p_prog[w], (uint32_t)s);
        out[t * NOUT + (k + 1)] = smp;
        const float lg = logf(p), lg1 = log1pf(-p);
        lp_acc[t]  += (smp > 0.5f) ? lg : lg1;
        ent_acc[t] -= (p * lg + (1.0f - p) * lg1);
      }
    }
    __syncthreads();
    // final outputs: logprobs (centered), entropies (mean over 47)
    red[tid] = lp_acc[tid] + lp_acc[tid + 256];
    __syncthreads();
    for (int off = 128; off > 0; off >>= 1) {
      if (tid < off) red[tid] += red[tid + off];
      __syncthreads();
    }
    const float mean = red[0] * (1.0f / 512.0f);
    out[24576 + tid]        = lp_acc[tid]        - mean;
    out[24576 + 256 + tid]  = lp_acc[tid + 256]  - mean;
    out[25088 + tid]        = ent_acc[tid]       * (1.0f / 47.0f);
    out[25088 + 256 + tid]  = ent_acc[tid + 256] * (1.0f / 47.0f);
    return;
  }

  // --------------------------- LSTM worker (R2) ---------------------------
  const int part = tid >> 6;          // column quarter 0..3
  const int r    = tid & 63;          // local row (gate*16 + jloc)
  const int gate = r >> 4;
  const int jloc = r & 15;
  const int row  = gate * 256 + blk * 16 + jloc;

  float wreg[64];
#pragma unroll
  for (int c = 0; c < 64; ++c)
    wreg[c] = W_hh[row * 256 + part * 64 + c];

  // Per-lane epilogue constants (lanes 0..63: lane = gate*16 + j).
  float bb = 0.f, wx0 = 0.f, wx1 = 0.f, mconst = 0.f, ml = 0.f, ad = 0.f;
  if (tid < 64) {
    const int g4 = tid >> 4;
    const int rr = g4 * 256 + blk * 16 + (tid & 15);
    bb  = b_ih[rr] + b_hh[rr];
    wx0 = W_ih[rr * 2 + 0];
    wx1 = W_ih[rr * 2 + 1];
    mconst = (g4 == 2) ? (-2.0f * LOG2E) : (-LOG2E);  // act = ml*sig(sc*x)+ad
    ml     = (g4 == 2) ? 2.0f : 1.0f;
    ad     = (g4 == 2) ? -1.0f : 0.0f;
  }

  if (tid == 0) {
    while (AL_ACQ(magic) != MAGIC_V) {}
  }
  __syncthreads();

  float c_st = 0.0f;                      // cell state (lanes tid<16)
  const int jglob = blk * 16 + (tid & 15);

  for (int s = 1; s <= NSTEP; ++s) {
    const int k = (s - 1) >> 9;
    const int t = (s - 1) & 511;
    const int par = s & 1;

    float samp = 0.0f, pv = 0.0f;
    if (tid == 255 && k > 0) {
      const uint32_t X = (uint32_t)((k - 1) * 512 + t + 1);
      while (AL_ACQ(&p_prog[t & 3]) < X) {}
      uint32_t* ob = (uint32_t*)(obsbuf + (k & 1) * (512 * 2) + t * 2);
      samp = __uint_as_float(AL_RELAX(&ob[0]));
      pv   = __uint_as_float(AL_RELAX(&ob[1]));
    }

    {  // 2-deep pipelined spin on own self-tagged word of h_{s-1}
      uint64_t* src = h_hist + (uint64_t)((s - 1) & 511) * 256 + tid;
      const uint32_t want = (uint32_t)(s - 1);
      uint64_t v = AL_RELAX(src);
      if ((uint32_t)(v >> 32) != want) {
        uint64_t a = AL_RELAX(src);
        uint64_t b = AL_RELAX(src);
        for (;;) {
          if ((uint32_t)(a >> 32) == want) { v = a; break; }
          a = AL_RELAX(src);
          if ((uint32_t)(b >> 32) == want) { v = b; break; }
          b = AL_RELAX(src);
        }
      }
      hstage[tid] = __uint_as_float((uint32_t)v);
    }
    if (tid == 255) { obs_s[par * 2 + 0] = samp; obs_s[par * 2 + 1] = pv; }
    BARRIER_LGKM();   // delta 1: no vmcnt(0) drain of the stale poll load

    float a0 = 0.f, a1 = 0.f, a2 = 0.f, a3 = 0.f;
    const float4* hs4 = (const float4*)(hstage + part * 64);
#pragma unroll
    for (int i = 0; i < 16; ++i) {
      const float4 hv = hs4[i];
      a0 = fmaf(wreg[4 * i + 0], hv.x, a0);
      a1 = fmaf(wreg[4 * i + 1], hv.y, a1);
      a2 = fmaf(wreg[4 * i + 2], hv.z, a2);
      a3 = fmaf(wreg[4 * i + 3], hv.w, a3);
    }
    plds[part][r] = (a0 + a1) + (a2 + a3);
    __syncthreads();

    if (tid < 64) {
      // One gate per lane: gv = full gate pre-activation.
      const float sx = obs_s[par * 2 + 0], px = obs_s[par * 2 + 1];
      const float base = wx0 * sx + wx1 * px + bb;
      const float gv = ((plds[0][tid] + plds[1][tid]) +
                        (plds[2][tid] + plds[3][tid])) + base;
      // act = sig(gv) for gates i,f,o; tanh(gv) = 2*sig(2gv)-1 for gate g.
      const float e   = __builtin_amdgcn_exp2f(gv * mconst);
      const float y   = __builtin_amdgcn_rcpf(1.0f + e);
      const float act = __builtin_fmaf(ml, y, ad);
      const int j = tid & 15;
      const float a_f = __shfl(act, j + 16, 64);
      const float a_g = __shfl(act, j + 32, 64);
      const float a_o = __shfl(act, j + 48, 64);
      if (tid < 16) {
        const float t1 = a_f * c_st;
        const float t2 = act * a_g;     // act = sig(i) on lanes 0..15
        c_st = t1 + t2;
        const float ec = __builtin_amdgcn_exp2f(c_st * (-2.0f * LOG2E));
        const float yc = __builtin_amdgcn_rcpf(1.0f + ec);
        const float th = __builtin_fmaf(2.0f, yc, -1.0f);
        const float hnew = a_o * th;
        AS_RELAX(&h_hist[(uint64_t)(s & 511) * 256 + jglob],
                 packht(hnew, (uint32_t)s));
      }
    }
  }
}

extern "C" void kernel_launch(void* const* d_in, const int* in_sizes, int n_in,
                              void* d_out, int out_size, void* d_ws, size_t ws_size,
                              hipStream_t stream) {
  const float* W_ih  = (const float*)d_in[0];
  const float* W_hh  = (const float*)d_in[1];
  const float* b_ih  = (const float*)d_in[2];
  const float* b_hh  = (const float*)d_in[3];
  const float* W_out = (const float*)d_in[4];
  const float* b_out = (const float*)d_in[5];
  float* out = (float*)d_out;
  uint64_t* ws = (uint64_t*)d_ws;

  arlstm_kernel<<<dim3(NWRK + 1), dim3(256), 0, stream>>>(
      W_ih, W_hh, b_ih, b_hh, W_out, b_out, out, ws);
}